// Round 12
// baseline (48.221 us; speedup 1.0000x reference)
//
#include <hip/hip_runtime.h>

// PiecewiseHawkesIntensity — np-golden semantics (FROZEN, established r0-r11):
//   inv = fl32(1/nc)  (correctly-rounded);  qn = fl32(q * inv)   [recip-mult key]
//   lo  = searchsorted_LEFT(ev, qn); last = lo-1
//   i = clip(last,0); t_last = (last==-1)?0:ev[last]; dt = qn - t_last
//   I = (mu_i + (alpha_i - mu_i)*exp(-beta_i*dt)) * inv
// r11 passed with absmax 0.0156 = bf16-compare floor.
//
// r12 change (scheduling only): m-dim split into 4 chunks of 8 -> grid 1024
// blocks x 512 threads = 4 blocks/CU (2048 thr = max occupancy), so barrier
// stalls of one block overlap another block's compute. ev/qt re-staged per
// chunk (L3-hit); mu/al/be still read exactly once.

constexpr int B  = 16;
constexpr int M  = 32;
constexpr int P  = 16;
constexpr int L  = 1024;
constexpr int LE = 2048;
constexpr int NC = 4;            // m-chunks
constexpr int MC = M / NC;       // 8 m's per chunk
constexpr int T  = 512;          // threads per block
constexpr int QT = LE / T;       // 4 queries per thread

__global__ __launch_bounds__(T)
void hawkes_kernel(const float* __restrict__ qt,   // [B,P,LE]
                   const float* __restrict__ ev,   // [B,P,L]
                   const float* __restrict__ mu,   // [B,M,P,L]
                   const float* __restrict__ al,   // [B,M,P,L]
                   const float* __restrict__ be,   // [B,M,P,L]
                   const float* __restrict__ nc,   // [B]
                   float* __restrict__ out)        // [B,M,P,LE]
{
    __shared__ float s_ev[L];
    __shared__ float s_mu[2][L];
    __shared__ float s_al[2][L];
    __shared__ float s_be[2][L];

    const int bid = blockIdx.x;         // 0..1023
    const int bp  = bid >> 2;           // (b,p)
    const int mc  = bid & (NC - 1);     // m-chunk
    const int b   = bp >> 4;
    const int p   = bp & (P - 1);
    const int t   = threadIdx.x;        // 0..511

    const float norm = nc[b];
    // correctly-rounded f32 reciprocal (np's key uses q * (1/nc))
    const float inv_norm = (float)(1.0 / (double)norm);

    // stage event row (4 KB) as float2, coalesced
    {
        const float2 e2 = *reinterpret_cast<const float2*>(ev + (size_t)bp * L + 2 * t);
        s_ev[2 * t]     = e2.x;
        s_ev[2 * t + 1] = e2.y;
    }

    // element offset of [b, mc*MC, p, 0] and m-stride
    const size_t row0 = (((size_t)b * M + mc * MC) * P + p) * L;
    const size_t mstr = (size_t)P * L;

    // prologue: stage first m of this chunk into buffer 0 (float2, coalesced)
    {
        const float2 m2 = *reinterpret_cast<const float2*>(mu + row0 + 2 * t);
        const float2 a2 = *reinterpret_cast<const float2*>(al + row0 + 2 * t);
        const float2 b2 = *reinterpret_cast<const float2*>(be + row0 + 2 * t);
        s_mu[0][2 * t] = m2.x; s_mu[0][2 * t + 1] = m2.y;
        s_al[0][2 * t] = a2.x; s_al[0][2 * t + 1] = a2.y;
        s_be[0][2 * t] = b2.x; s_be[0][2 * t + 1] = b2.y;
    }

    __syncthreads();   // s_ev visible

    // QT queries per thread: q = t + j*T  (coalesced)
    const float* qrow = qt + (size_t)bp * LE;
    int   idx[QT];
    float dt[QT];
#pragma unroll
    for (int j = 0; j < QT; ++j) {
        // np's key: q * (1/nc), both IEEE f32 (reciprocal-multiply idiom)
        const float qn = __fmul_rn(qrow[t + j * T], inv_norm);
        // searchsorted-LEFT: first lo with ev[lo] >= qn.
        // Convergence-tested loop; always in-bounds: lo <= mid < hi <= L.
        int lo = 0, hi = L;
        while (lo < hi) {
            const int mid = (lo + hi) >> 1;
            if (s_ev[mid] < qn) lo = mid + 1; else hi = mid;
        }
        const int last = lo - 1;           // -1 if qn <= ev[0]; L-1 if beyond last
        const int   i  = (last < 0) ? 0    : last;
        const float tl = (last < 0) ? 0.0f : s_ev[last];
        idx[j] = i;
        dt[j]  = __fmul_rn(qn, 1.0f) - tl; // plain f32 subtract (qn - tl)
    }

    const size_t obase0 = (((size_t)b * M + mc * MC) * P + p) * LE;

    for (int mi = 0; mi < MC; ++mi) {
        __syncthreads();                 // buf[mi&1] staged (prev iter / prologue) visible;
                                         // all readers of buf[(mi+1)&1] done
        const int cur = mi & 1;
        if (mi + 1 < MC) {
            const size_t r  = row0 + (size_t)(mi + 1) * mstr;
            const int   nxt = cur ^ 1;
            const float2 m2 = *reinterpret_cast<const float2*>(mu + r + 2 * t);
            const float2 a2 = *reinterpret_cast<const float2*>(al + r + 2 * t);
            const float2 b2 = *reinterpret_cast<const float2*>(be + r + 2 * t);
            s_mu[nxt][2 * t] = m2.x; s_mu[nxt][2 * t + 1] = m2.y;
            s_al[nxt][2 * t] = a2.x; s_al[nxt][2 * t + 1] = a2.y;
            s_be[nxt][2 * t] = b2.x; s_be[nxt][2 * t + 1] = b2.y;
        }
        float* orow = out + obase0 + (size_t)mi * mstr * 2;   // mstr*2 == P*LE
#pragma unroll
        for (int j = 0; j < QT; ++j) {
            const float m0 = s_mu[cur][idx[j]];
            const float a0 = s_al[cur][idx[j]];
            const float b0 = s_be[cur][idx[j]];
            const float v  = fmaf(a0 - m0, __expf(-b0 * dt[j]), m0) * inv_norm;
            orow[t + j * T] = v;
        }
    }
}

extern "C" void kernel_launch(void* const* d_in, const int* in_sizes, int n_in,
                              void* d_out, int out_size, void* d_ws, size_t ws_size,
                              hipStream_t stream) {
    const float* qt = (const float*)d_in[0];
    const float* ev = (const float*)d_in[1];
    const float* mu = (const float*)d_in[2];
    const float* al = (const float*)d_in[3];
    const float* be = (const float*)d_in[4];
    const float* nc = (const float*)d_in[5];
    float* out = (float*)d_out;

    hawkes_kernel<<<B * P * NC, T, 0, stream>>>(qt, ev, mu, al, be, nc, out);
}

// Round 13
// 33.190 us; speedup vs baseline: 1.4529x; 1.4529x over previous
//
#include <hip/hip_runtime.h>

// PiecewiseHawkesIntensity — np-golden semantics (FROZEN since r11, passed):
//   inv = fl32(1/nc) (CR);  qn = fl32(q * inv)   [reciprocal-multiply key]
//   lo = searchsorted_LEFT(ev, qn); last = lo-1
//   i = clip(last,0); t_last = (last==-1)?0:ev[last]; dt = qn - t_last  (f32)
//   I = (mu_i + (alpha_i - mu_i)*exp(-beta_i*dt)) * inv
//
// r13 (scheduling only): T14 async-STAGE split. Loads for row m+2 issued into
// REGISTERS at the top of each sub-iter (they survive __syncthreads -- only the
// ds_write waits on them), ds_write of row m+1 happens after the epilogue.
// 2-step manual unroll with two named register trios (no reg-reg rotation =>
// no spurious vmcnt waits). Grid stays 256 x 1024 (zero redundancy; r12's
// 4-chunk split was a single launch wave -> no cross-block overlap, +13us).

constexpr int B  = 16;
constexpr int M  = 32;
constexpr int P  = 16;
constexpr int L  = 1024;
constexpr int LE = 2048;

__global__ __launch_bounds__(1024)
void hawkes_kernel(const float* __restrict__ qt,   // [B,P,LE]
                   const float* __restrict__ ev,   // [B,P,L]
                   const float* __restrict__ mu,   // [B,M,P,L]
                   const float* __restrict__ al,   // [B,M,P,L]
                   const float* __restrict__ be,   // [B,M,P,L]
                   const float* __restrict__ nc,   // [B]
                   float* __restrict__ out)        // [B,M,P,LE]
{
    __shared__ float s_ev[L];
    __shared__ float s_mu[2][L];
    __shared__ float s_al[2][L];
    __shared__ float s_be[2][L];

    const int bp = blockIdx.x;          // 0..255  -> (b,p)
    const int b  = bp >> 4;
    const int p  = bp & (P - 1);
    const int t  = threadIdx.x;         // 0..1023

    const float norm     = nc[b];
    const float inv_norm = (float)(1.0 / (double)norm);   // CR f32 recip

    const size_t row0 = ((size_t)b * M * P + p) * L;   // [b,0,p,0]
    const size_t mstr = (size_t)P * L;                 // m-stride

    // issue everything independent up front: ev row, param rows m0,m1
    const float e_in = ev[(size_t)bp * L + t];
    float rA_mu = mu[row0 + t],        rA_al = al[row0 + t],        rA_be = be[row0 + t];
    float rB_mu = mu[row0 + mstr + t], rB_al = al[row0 + mstr + t], rB_be = be[row0 + mstr + t];

    s_ev[t]    = e_in;
    s_mu[0][t] = rA_mu;  s_al[0][t] = rA_al;  s_be[0][t] = rA_be;   // buf0 = m0

    __syncthreads();   // s_ev + buf0 visible (rB_* still in flight)

    // two ADJACENT queries per thread (float2 I/O), fixed-trip interleaved search
    const float2 q2 = *reinterpret_cast<const float2*>(qt + (size_t)bp * LE + 2 * t);
    int   idx[2];
    float dtv[2];
    {
        float qn[2] = { __fmul_rn(q2.x, inv_norm), __fmul_rn(q2.y, inv_norm) };
        int lo[2] = {0, 0}, hi[2] = {L, L};
#pragma unroll
        for (int s = 0; s < 11; ++s) {     // max path length over 1025 answers
#pragma unroll
            for (int k = 0; k < 2; ++k) {
                if (lo[k] < hi[k]) {       // guard: converged lanes stay put
                    const int mid = (lo[k] + hi[k]) >> 1;
                    if (s_ev[mid] < qn[k]) lo[k] = mid + 1; else hi[k] = mid;
                }
            }
        }
#pragma unroll
        for (int k = 0; k < 2; ++k) {
            const int last = lo[k] - 1;          // -1 if qn <= ev[0]
            idx[k] = (last < 0) ? 0    : last;
            const float tl = (last < 0) ? 0.0f : s_ev[idx[k]];
            dtv[k] = qn[k] - tl;
        }
    }

    float* const obase = out + ((size_t)b * M * P + p) * LE + 2 * t;

#pragma unroll 1
    for (int m = 0; m < M; m += 2) {
        // ---- sub-iter A: compute row m from buf0; rA free -> issue row m+2
        if (m + 2 < M) {
            const size_t r = row0 + (size_t)(m + 2) * mstr;
            rA_mu = mu[r + t];  rA_al = al[r + t];  rA_be = be[r + t];
        }
        {
            float2 o;
            {
                const float m0 = s_mu[0][idx[0]], a0 = s_al[0][idx[0]], b0 = s_be[0][idx[0]];
                o.x = fmaf(a0 - m0, __expf(-b0 * dtv[0]), m0) * inv_norm;
            }
            {
                const float m1 = s_mu[0][idx[1]], a1 = s_al[0][idx[1]], b1 = s_be[0][idx[1]];
                o.y = fmaf(a1 - m1, __expf(-b1 * dtv[1]), m1) * inv_norm;
            }
            *reinterpret_cast<float2*>(obase + (size_t)m * (P * LE)) = o;
        }
        // write row m+1 (rB, issued 2 sub-iters ago) into buf1
        s_mu[1][t] = rB_mu;  s_al[1][t] = rB_al;  s_be[1][t] = rB_be;
        __syncthreads();   // buf1 visible; all readers of buf0 done

        // ---- sub-iter B: compute row m+1 from buf1; rB free -> issue row m+3
        if (m + 3 < M) {
            const size_t r = row0 + (size_t)(m + 3) * mstr;
            rB_mu = mu[r + t];  rB_al = al[r + t];  rB_be = be[r + t];
        }
        {
            float2 o;
            {
                const float m0 = s_mu[1][idx[0]], a0 = s_al[1][idx[0]], b0 = s_be[1][idx[0]];
                o.x = fmaf(a0 - m0, __expf(-b0 * dtv[0]), m0) * inv_norm;
            }
            {
                const float m1 = s_mu[1][idx[1]], a1 = s_al[1][idx[1]], b1 = s_be[1][idx[1]];
                o.y = fmaf(a1 - m1, __expf(-b1 * dtv[1]), m1) * inv_norm;
            }
            *reinterpret_cast<float2*>(obase + (size_t)(m + 1) * (P * LE)) = o;
        }
        // write row m+2 (rA) into buf0
        if (m + 2 < M) {
            s_mu[0][t] = rA_mu;  s_al[0][t] = rA_al;  s_be[0][t] = rA_be;
        }
        __syncthreads();   // buf0 visible; all readers of buf1 done
    }
}

extern "C" void kernel_launch(void* const* d_in, const int* in_sizes, int n_in,
                              void* d_out, int out_size, void* d_ws, size_t ws_size,
                              hipStream_t stream) {
    const float* qt = (const float*)d_in[0];
    const float* ev = (const float*)d_in[1];
    const float* mu = (const float*)d_in[2];
    const float* al = (const float*)d_in[3];
    const float* be = (const float*)d_in[4];
    const float* nc = (const float*)d_in[5];
    float* out = (float*)d_out;

    hawkes_kernel<<<B * P, 1024, 0, stream>>>(qt, ev, mu, al, be, nc, out);
}